// Round 1
// baseline (730.232 us; speedup 1.0000x reference)
//
#include <hip/hip_runtime.h>
#include <hip/hip_bf16.h>

#define NN    100000
#define NEDGE 1250000
#define DD    64
#define HH    8
#define DHH   8

typedef __attribute__((ext_vector_type(8))) short bf16x8;
typedef __attribute__((ext_vector_type(4))) float f32x4;

__device__ __forceinline__ short f2bf(float f) {
    unsigned u = __float_as_uint(f);
    u += 0x7FFFu + ((u >> 16) & 1u);   // round-to-nearest-even
    return (short)(u >> 16);
}

// ---------------- Kernel 1: Q,K,V = x @ {WQ,WK,WV}  (bf16 MFMA, fp32 out) ---
__global__ __launch_bounds__(256) void qkv_kernel(
    const float* __restrict__ x,
    const float* __restrict__ WQ, const float* __restrict__ WK,
    const float* __restrict__ WV,
    float* __restrict__ Q, float* __restrict__ K, float* __restrict__ V)
{
    const int lane = threadIdx.x & 63;
    const int wid  = threadIdx.x >> 6;
    const int gw   = blockIdx.x * 4 + wid;
    const int nw   = gridDim.x * 4;
    const int colb = lane & 15;
    const int krow = (lane >> 4) * 8;

    // B fragments: 3 matrices x 4 col-tiles x 2 k-halves (96 VGPRs)
    bf16x8 Bf[3][4][2];
    const float* Ws[3] = {WQ, WK, WV};
    #pragma unroll
    for (int m = 0; m < 3; ++m)
        #pragma unroll
        for (int n = 0; n < 4; ++n)
            #pragma unroll
            for (int kh = 0; kh < 2; ++kh) {
                bf16x8 b;
                #pragma unroll
                for (int j = 0; j < 8; ++j)
                    b[j] = f2bf(Ws[m][(size_t)(kh * 32 + krow + j) * 64 + n * 16 + colb]);
                Bf[m][n][kh] = b;
            }

    float* Outs[3] = {Q, K, V};

    for (int tile = gw; tile < NN / 16; tile += nw) {
        const int r0 = tile * 16;
        const float* xr = x + (size_t)(r0 + colb) * 64 + krow;
        f32x4 a0 = *(const f32x4*)(xr);
        f32x4 a1 = *(const f32x4*)(xr + 4);
        f32x4 a2 = *(const f32x4*)(xr + 32);
        f32x4 a3 = *(const f32x4*)(xr + 36);
        bf16x8 Alo, Ahi;
        #pragma unroll
        for (int j = 0; j < 4; ++j) {
            Alo[j]     = f2bf(a0[j]);
            Alo[4 + j] = f2bf(a1[j]);
            Ahi[j]     = f2bf(a2[j]);
            Ahi[4 + j] = f2bf(a3[j]);
        }

        #pragma unroll
        for (int m = 0; m < 3; ++m) {
            #pragma unroll
            for (int n = 0; n < 4; ++n) {
                f32x4 acc = {0.f, 0.f, 0.f, 0.f};
                acc = __builtin_amdgcn_mfma_f32_16x16x32_bf16(Alo, Bf[m][n][0], acc, 0, 0, 0);
                acc = __builtin_amdgcn_mfma_f32_16x16x32_bf16(Ahi, Bf[m][n][1], acc, 0, 0, 0);
                #pragma unroll
                for (int q = 0; q < 4; ++q)
                    Outs[m][(size_t)(r0 + (lane >> 4) * 4 + q) * 64 + n * 16 + colb] = acc[q];
            }
        }
    }
}

// ---------------- Kernel 2: fused Ef GEMM + score + scatter --------------
__global__ __launch_bounds__(256) void edge_kernel(
    const float* __restrict__ edge_attr, const float* __restrict__ WE,
    const float* __restrict__ Qn, const float* __restrict__ Kn,
    const float* __restrict__ Vn, const int* __restrict__ ei,
    float* __restrict__ outAcc, float* __restrict__ Z)
{
    const int lane = threadIdx.x & 63;
    const int wid  = threadIdx.x >> 6;
    const int gw   = blockIdx.x * 4 + wid;
    const int nw   = gridDim.x * 4;
    const int colb = lane & 15;
    const int krow = (lane >> 4) * 8;
    const int b8   = (lane >> 3) & 1;      // high/low 8 of the 16-lane col group

    // WE fragments: 4 col-tiles x 2 k-halves (32 VGPRs), loaded once
    bf16x8 Bf[4][2];
    #pragma unroll
    for (int n = 0; n < 4; ++n)
        #pragma unroll
        for (int kh = 0; kh < 2; ++kh) {
            bf16x8 b;
            #pragma unroll
            for (int j = 0; j < 8; ++j)
                b[j] = f2bf(WE[(size_t)(kh * 32 + krow + j) * 64 + n * 16 + colb]);
            Bf[n][kh] = b;
        }

    const float inv_sqrt_dh = 0.35355339059327373f;  // 1/sqrt(8)

    for (int tile = gw; tile < NEDGE / 16; tile += nw) {
        const int e0 = tile * 16;

        // A fragment: 16 contiguous edge_attr rows (coalesced 4 KB per wave)
        const float* ear = edge_attr + (size_t)(e0 + colb) * 64 + krow;
        f32x4 a0 = *(const f32x4*)(ear);
        f32x4 a1 = *(const f32x4*)(ear + 4);
        f32x4 a2 = *(const f32x4*)(ear + 32);
        f32x4 a3 = *(const f32x4*)(ear + 36);
        bf16x8 Alo, Ahi;
        #pragma unroll
        for (int j = 0; j < 4; ++j) {
            Alo[j]     = f2bf(a0[j]);
            Alo[4 + j] = f2bf(a1[j]);
            Ahi[j]     = f2bf(a2[j]);
            Ahi[4 + j] = f2bf(a3[j]);
        }

        // Ef tile: 16 edges x 64 cols, accumulated fp32
        f32x4 acc[4];
        #pragma unroll
        for (int n = 0; n < 4; ++n) {
            f32x4 z = {0.f, 0.f, 0.f, 0.f};
            z = __builtin_amdgcn_mfma_f32_16x16x32_bf16(Alo, Bf[n][0], z, 0, 0, 0);
            z = __builtin_amdgcn_mfma_f32_16x16x32_bf16(Ahi, Bf[n][1], z, 0, 0, 0);
            acc[n] = z;
        }

        // edge endpoints for this lane's 4 edge-rows
        int srcq[4], dstq[4];
        #pragma unroll
        for (int q = 0; q < 4; ++q) {
            const int erl = (lane >> 4) * 4 + q;
            srcq[q] = ei[e0 + erl];
            dstq[q] = ei[NEDGE + e0 + erl];
        }

        // scores: per (edge q, col-tile n) -> head h = 2n + b8
        float sc[4][4];
        #pragma unroll
        for (int q = 0; q < 4; ++q) {
            #pragma unroll
            for (int n = 0; n < 4; ++n) {
                const int c = n * 16 + colb;
                const float kv = Kn[(size_t)srcq[q] * 64 + c];
                const float qv = Qn[(size_t)dstq[q] * 64 + c];
                float t = kv * qv * acc[n][q];
                t += __shfl_xor(t, 1);
                t += __shfl_xor(t, 2);
                t += __shfl_xor(t, 4);
                float s = fminf(fmaxf(t * inv_sqrt_dh, -5.0f), 5.0f);
                sc[q][n] = __expf(s);
            }
        }

        // message scatter + denominator
        #pragma unroll
        for (int q = 0; q < 4; ++q) {
            #pragma unroll
            for (int n = 0; n < 4; ++n) {
                const int c = n * 16 + colb;
                const float vv = Vn[(size_t)srcq[q] * 64 + c];
                unsafeAtomicAdd(&outAcc[(size_t)dstq[q] * 64 + c], vv * sc[q][n]);
                if ((lane & 7) == 0) {
                    const int h = 2 * n + b8;
                    unsafeAtomicAdd(&Z[(size_t)dstq[q] * 8 + h], sc[q][n]);
                }
            }
        }
    }
}

// ---------------- Kernel 3: out = wV / (Z + 1e-6) ------------------------
__global__ __launch_bounds__(256) void finalize_kernel(
    float* __restrict__ out, const float* __restrict__ Z)
{
    const int i = blockIdx.x * blockDim.x + threadIdx.x;
    if (i < NN * 64) {
        const int node = i >> 6;
        const int h    = (i >> 3) & 7;
        out[i] = out[i] / (Z[node * 8 + h] + 1e-6f);
    }
}

extern "C" void kernel_launch(void* const* d_in, const int* in_sizes, int n_in,
                              void* d_out, int out_size, void* d_ws, size_t ws_size,
                              hipStream_t stream) {
    const float* x         = (const float*)d_in[0];
    const float* edge_attr = (const float*)d_in[1];
    const float* WQ        = (const float*)d_in[2];
    const float* WK        = (const float*)d_in[3];
    const float* WV        = (const float*)d_in[4];
    const float* WE        = (const float*)d_in[5];
    const int*   ei        = (const int*)d_in[6];
    float* out = (float*)d_out;

    float* Q = (float*)d_ws;                 // N*64 f32
    float* K = Q + (size_t)NN * 64;          // N*64 f32
    float* V = K + (size_t)NN * 64;          // N*64 f32
    float* Z = V + (size_t)NN * 64;          // N*8  f32
    // total ws: 80 MB

    hipMemsetAsync(d_out, 0, (size_t)NN * 64 * sizeof(float), stream);
    hipMemsetAsync(Z, 0, (size_t)NN * 8 * sizeof(float), stream);

    qkv_kernel<<<1024, 256, 0, stream>>>(x, WQ, WK, WV, Q, K, V);
    edge_kernel<<<2048, 256, 0, stream>>>(edge_attr, WE, Q, K, V, ei, out, Z);
    finalize_kernel<<<(NN * 64 + 255) / 256, 256, 0, stream>>>(out, Z);
}